// Round 1
// baseline (257.447 us; speedup 1.0000x reference)
//
#include <hip/hip_runtime.h>

using u16 = unsigned short;
using u32 = unsigned int;

typedef __bf16 bf16x8 __attribute__((ext_vector_type(8)));
typedef float f32x4 __attribute__((ext_vector_type(4)));

__device__ __forceinline__ u16 f2b(float x) {
  u32 u = __builtin_bit_cast(u32, x);
  u += 0x7fffu + ((u >> 16) & 1u);   // RNE
  return (u16)(u >> 16);
}

__device__ __forceinline__ void gload16(const u16* g, u16* l) {
  __builtin_amdgcn_global_load_lds(
      (const __attribute__((address_space(1))) void*)g,
      (__attribute__((address_space(3))) void*)l, 16, 0, 0);
}

// ---------------- fp32 -> bf16 convert (8 elems/thread) ----------------
__global__ void cvt_bf16_k(const float* __restrict__ s, u16* __restrict__ d, int n8) {
  int i = blockIdx.x * blockDim.x + threadIdx.x;
  int stride = gridDim.x * blockDim.x;
  for (; i < n8; i += stride) {
    float4 a = ((const float4*)s)[2 * i];
    float4 b = ((const float4*)s)[2 * i + 1];
    uint4 o;
    o.x = (u32)f2b(a.x) | ((u32)f2b(a.y) << 16);
    o.y = (u32)f2b(a.z) | ((u32)f2b(a.w) << 16);
    o.z = (u32)f2b(b.x) | ((u32)f2b(b.y) << 16);
    o.w = (u32)f2b(b.z) | ((u32)f2b(b.w) << 16);
    ((uint4*)d)[i] = o;
  }
}

// ---------------- bf16 GEMM, C = A * B^T (+bias), m97 structure ----------------
// A: [M,1024] row-major bf16. Bm: [N,1024] row-major bf16 (i.e. torch Linear weight).
// MODE 0: N=3072, scatter bf16 into q/k/v [B=2,H=16,S=2048,64].
// MODE 1: N=1024, write fp32 to outf [M,1024].
template <int MODE>
__global__ __launch_bounds__(256) void gemm_bt(
    const u16* __restrict__ A, const u16* __restrict__ Bm,
    const float* __restrict__ bias,
    u16* __restrict__ q, u16* __restrict__ k, u16* __restrict__ v,
    float* __restrict__ outf) {
  constexpr int KD = 1024;
  const int n0 = blockIdx.x * 128;
  const int m0 = blockIdx.y * 128;
  const int tid = threadIdx.x;
  const int wid = tid >> 6;
  const int lane = tid & 63;
  const int wr = wid >> 1, wc = wid & 1;   // 2x2 waves, 64x64 each
  const int fr = lane & 15, fg = lane >> 4;
  const int srow = lane >> 2;              // staging row within 16
  const int scol = (lane & 3) * 8;         // staging col (elements)

  __shared__ __align__(16) u16 As[128 * 32];
  __shared__ __align__(16) u16 Bs[128 * 32];

  f32x4 acc[4][4] = {};

  for (int k0 = 0; k0 < KD; k0 += 32) {
#pragma unroll
    for (int i = 0; i < 2; ++i) {
      int row = i * 64 + wid * 16 + srow;
      gload16(A + (size_t)(m0 + row) * KD + k0 + scol, As + (i * 64 + wid * 16) * 32);
      gload16(Bm + (size_t)(n0 + row) * KD + k0 + scol, Bs + (i * 64 + wid * 16) * 32);
    }
    __syncthreads();   // compiler drains vmcnt before barrier -> tile staged
    bf16x8 af[4], bfr[4];
#pragma unroll
    for (int r = 0; r < 4; ++r) {
      af[r]  = *(const bf16x8*)(As + (wr * 64 + r * 16 + fr) * 32 + fg * 8);
      bfr[r] = *(const bf16x8*)(Bs + (wc * 64 + r * 16 + fr) * 32 + fg * 8);
    }
#pragma unroll
    for (int r = 0; r < 4; ++r)
#pragma unroll
      for (int c = 0; c < 4; ++c)
        acc[r][c] = __builtin_amdgcn_mfma_f32_16x16x32_bf16(af[r], bfr[c], acc[r][c], 0, 0, 0);
    __syncthreads();   // reads done before next stage overwrites
  }

#pragma unroll
  for (int r = 0; r < 4; ++r) {
#pragma unroll
    for (int c = 0; c < 4; ++c) {
      const int gcol = n0 + wc * 64 + c * 16 + fr;
      const float bv = bias[gcol];
#pragma unroll
      for (int g = 0; g < 4; ++g) {
        const int grow = m0 + wr * 64 + r * 16 + fg * 4 + g;
        const float val = acc[r][c][g] + bv;
        if (MODE == 0) {
          const int which = gcol >> 10;          // 0=q 1=k 2=v
          const int dcol = gcol & 1023;
          const int hh = dcol >> 6, dd = dcol & 63;
          const int bb = grow >> 11, ss = grow & 2047;
          u16* dst = which == 0 ? q : (which == 1 ? k : v);
          dst[((size_t)((bb << 4) + hh) * 2048 + ss) * 64 + dd] = f2b(val);
        } else {
          outf[(size_t)grow * 1024 + gcol] = val;
        }
      }
    }
  }
}

// ---------------- flash attention fwd, bf16 MFMA, online softmax ----------------
// Q,K,V: [32 bh][2048][64] bf16.  AO: [4096][1024] bf16 ([b*2048+s][h*64+d]).
__global__ __launch_bounds__(256) void attn_fwd(
    const u16* __restrict__ Q, const u16* __restrict__ K,
    const u16* __restrict__ V, u16* __restrict__ AO) {
  // bijective XCD swizzle: 512 wgs, XCD x gets bh-contiguous chunk (KV stays L2-hot)
  const int wg = blockIdx.x;                // 0..511
  const int newid = (wg & 7) * 64 + (wg >> 3);
  const int bh = newid >> 4;                // 0..31
  const int qt = newid & 15;                // 0..15
  const int b = bh >> 4, h = bh & 15;

  const int tid = threadIdx.x, wid = tid >> 6, lane = tid & 63;
  const int fr = lane & 15, fg = lane >> 4;
  const size_t base = (size_t)bh * (2048 * 64);
  const int q0 = qt * 128 + wid * 32;       // wave's first q row (in-sequence)

  constexpr int LD = 72;                    // padded stride (144B): 2-way banks = free
  __shared__ __align__(16) u16 Ks[64 * LD];
  __shared__ __align__(16) u16 Vs[64 * LD]; // transposed: Vs[d][key]
  __shared__ __align__(16) u16 Ps[4][32 * LD];

  // Q hoisted to registers (A-frag layout)
  bf16x8 qf[2][2];
#pragma unroll
  for (int rf = 0; rf < 2; ++rf)
#pragma unroll
    for (int ks = 0; ks < 2; ++ks)
      qf[rf][ks] = *(const bf16x8*)(Q + base + (size_t)(q0 + rf * 16 + fr) * 64 + ks * 32 + fg * 8);

  f32x4 o[2][4] = {};
  float mrow[2][4], lrow[2][4];
#pragma unroll
  for (int rf = 0; rf < 2; ++rf)
#pragma unroll
    for (int g = 0; g < 4; ++g) { mrow[rf][g] = -1e30f; lrow[rf][g] = 0.f; }

  const int krow = lane;        // staging: lane-per-row, wave covers cols wid*16..+16
  const int c0 = wid * 16;

  uint4 k0r, k1r, v0r, v1r;
  {
    const u16* kp = K + base + (size_t)krow * 64 + c0;
    const u16* vp = V + base + (size_t)krow * 64 + c0;
    k0r = *(const uint4*)kp; k1r = *(const uint4*)(kp + 8);
    v0r = *(const uint4*)vp; v1r = *(const uint4*)(vp + 8);
  }

  for (int t = 0; t < 32; ++t) {
    __syncthreads();            // previous tile's LDS reads done
    *(uint4*)(Ks + krow * LD + c0) = k0r;
    *(uint4*)(Ks + krow * LD + c0 + 8) = k1r;
    {
      u32 vv[8] = {v0r.x, v0r.y, v0r.z, v0r.w, v1r.x, v1r.y, v1r.z, v1r.w};
#pragma unroll
      for (int j = 0; j < 8; ++j) {   // transpose-store V: contiguous per instr = free
        Vs[(c0 + 2 * j) * LD + krow]     = (u16)(vv[j] & 0xffffu);
        Vs[(c0 + 2 * j + 1) * LD + krow] = (u16)(vv[j] >> 16);
      }
    }
    if (t + 1 < 32) {           // T14: issue next tile's loads, hide under compute
      const u16* kp = K + base + (size_t)((t + 1) * 64 + krow) * 64 + c0;
      const u16* vp = V + base + (size_t)((t + 1) * 64 + krow) * 64 + c0;
      k0r = *(const uint4*)kp; k1r = *(const uint4*)(kp + 8);
      v0r = *(const uint4*)vp; v1r = *(const uint4*)(vp + 8);
    }
    __syncthreads();            // tile staged

    // S = Q K^T (scaled)
    f32x4 s[2][4];
    bf16x8 kf[4][2];
#pragma unroll
    for (int c = 0; c < 4; ++c)
#pragma unroll
      for (int ks = 0; ks < 2; ++ks)
        kf[c][ks] = *(const bf16x8*)(Ks + (c * 16 + fr) * LD + ks * 32 + fg * 8);
#pragma unroll
    for (int rf = 0; rf < 2; ++rf)
#pragma unroll
      for (int c = 0; c < 4; ++c) {
        f32x4 z = {};
        z = __builtin_amdgcn_mfma_f32_16x16x32_bf16(qf[rf][0], kf[c][0], z, 0, 0, 0);
        z = __builtin_amdgcn_mfma_f32_16x16x32_bf16(qf[rf][1], kf[c][1], z, 0, 0, 0);
        s[rf][c] = z * 0.125f;  // 1/sqrt(64)
      }

    // online softmax; rows owned lane-locally (row=(lane>>4)*4+g), cols across 16-lane group
#pragma unroll
    for (int rf = 0; rf < 2; ++rf) {
#pragma unroll
      for (int g = 0; g < 4; ++g) {
        float mx = fmaxf(fmaxf(s[rf][0][g], s[rf][1][g]), fmaxf(s[rf][2][g], s[rf][3][g]));
        mx = fmaxf(mx, __shfl_xor(mx, 1));
        mx = fmaxf(mx, __shfl_xor(mx, 2));
        mx = fmaxf(mx, __shfl_xor(mx, 4));
        mx = fmaxf(mx, __shfl_xor(mx, 8));
        const float mold = mrow[rf][g];
        const float mnew = fmaxf(mold, mx);
        const float corr = __expf(mold - mnew);
        mrow[rf][g] = mnew;
        float rs = 0.f;
#pragma unroll
        for (int c = 0; c < 4; ++c) {
          const float p = __expf(s[rf][c][g] - mnew);
          s[rf][c][g] = p;
          rs += p;
        }
        rs += __shfl_xor(rs, 1);
        rs += __shfl_xor(rs, 2);
        rs += __shfl_xor(rs, 4);
        rs += __shfl_xor(rs, 8);
        lrow[rf][g] = lrow[rf][g] * corr + rs;
#pragma unroll
        for (int d = 0; d < 4; ++d) o[rf][d][g] *= corr;
      }
    }

    // P -> bf16 -> per-wave LDS (C-layout -> A-frag layout transpose)
    u16* pw = (u16*)Ps[wid];
#pragma unroll
    for (int rf = 0; rf < 2; ++rf)
#pragma unroll
      for (int c = 0; c < 4; ++c)
#pragma unroll
        for (int g = 0; g < 4; ++g)
          pw[(rf * 16 + fg * 4 + g) * LD + c * 16 + fr] = f2b(s[rf][c][g]);
    asm volatile("s_waitcnt lgkmcnt(0)" ::: "memory");  // wave-local write->read fence

    bf16x8 pf[2][2], vf[4][2];
#pragma unroll
    for (int rf = 0; rf < 2; ++rf)
#pragma unroll
      for (int ks = 0; ks < 2; ++ks)
        pf[rf][ks] = *(const bf16x8*)(pw + (rf * 16 + fr) * LD + ks * 32 + fg * 8);
#pragma unroll
    for (int d = 0; d < 4; ++d)
#pragma unroll
      for (int ks = 0; ks < 2; ++ks)
        vf[d][ks] = *(const bf16x8*)(Vs + (d * 16 + fr) * LD + ks * 32 + fg * 8);
#pragma unroll
    for (int rf = 0; rf < 2; ++rf)
#pragma unroll
      for (int d = 0; d < 4; ++d) {
        o[rf][d] = __builtin_amdgcn_mfma_f32_16x16x32_bf16(pf[rf][0], vf[d][0], o[rf][d], 0, 0, 0);
        o[rf][d] = __builtin_amdgcn_mfma_f32_16x16x32_bf16(pf[rf][1], vf[d][1], o[rf][d], 0, 0, 0);
      }
  }

  // epilogue: O/l -> bf16 [b*2048+s][h*64+d]
#pragma unroll
  for (int rf = 0; rf < 2; ++rf)
#pragma unroll
    for (int d = 0; d < 4; ++d)
#pragma unroll
      for (int g = 0; g < 4; ++g) {
        const int qr = q0 + rf * 16 + fg * 4 + g;
        const int dc = d * 16 + fr;
        const float val = o[rf][d][g] / lrow[rf][g];
        AO[(size_t)(b * 2048 + qr) * 1024 + h * 64 + dc] = f2b(val);
      }
}

// ---------------- launch ----------------
extern "C" void kernel_launch(void* const* d_in, const int* in_sizes, int n_in,
                              void* d_out, int out_size, void* d_ws, size_t ws_size,
                              hipStream_t stream) {
  (void)in_sizes; (void)n_in; (void)out_size; (void)ws_size;
  const float* x     = (const float*)d_in[0];
  const float* w_in  = (const float*)d_in[1];
  const float* b_in  = (const float*)d_in[2];
  const float* w_out = (const float*)d_in[3];
  const float* b_out = (const float*)d_in[4];

  // workspace layout (bf16 elements); total 48 MB
  u16* xb    = (u16*)d_ws;                       // [4096,1024]
  u16* winb  = xb    + (size_t)4096 * 1024;      // [3072,1024]
  u16* woutb = winb  + (size_t)3072 * 1024;      // [1024,1024]
  u16* qb    = woutb + (size_t)1024 * 1024;      // [32,2048,64]
  u16* kb    = qb    + (size_t)4194304;
  u16* vb    = kb    + (size_t)4194304;
  u16* aob   = vb    + (size_t)4194304;          // [4096,1024]

  cvt_bf16_k<<<2048, 256, 0, stream>>>(x, xb, 4096 * 1024 / 8);
  cvt_bf16_k<<<1536, 256, 0, stream>>>(w_in, winb, 3072 * 1024 / 8);
  cvt_bf16_k<<<512, 256, 0, stream>>>(w_out, woutb, 1024 * 1024 / 8);

  gemm_bt<0><<<dim3(24, 32), 256, 0, stream>>>(xb, winb, b_in, qb, kb, vb, nullptr);
  attn_fwd<<<512, 256, 0, stream>>>(qb, kb, vb, aob);
  gemm_bt<1><<<dim3(8, 32), 256, 0, stream>>>(aob, woutb, b_out, nullptr, nullptr, nullptr,
                                              (float*)d_out);
}

// Round 2
// 221.954 us; speedup vs baseline: 1.1599x; 1.1599x over previous
//
#include <hip/hip_runtime.h>

using u16 = unsigned short;
using u32 = unsigned int;

typedef __bf16 bf16x8 __attribute__((ext_vector_type(8)));
typedef __bf16 bf16x2 __attribute__((ext_vector_type(2)));
typedef float f32x4 __attribute__((ext_vector_type(4)));

__device__ __forceinline__ u16 f2b(float x) {
  u32 u = __builtin_bit_cast(u32, x);
  u += 0x7fffu + ((u >> 16) & 1u);   // RNE
  return (u16)(u >> 16);
}

// pack two f32 -> bf16x2 (low = first). Compiler emits v_cvt_pk_bf16_f32.
__device__ __forceinline__ u32 pk2(float lo, float hi) {
  bf16x2 t;
  t[0] = (__bf16)lo;
  t[1] = (__bf16)hi;
  return __builtin_bit_cast(u32, t);
}

__device__ __forceinline__ void gload16(const u16* g, u16* l) {
  __builtin_amdgcn_global_load_lds(
      (const __attribute__((address_space(1))) void*)g,
      (__attribute__((address_space(3))) void*)l, 16, 0, 0);
}

#define SCALE_Q 0.1803368801111204f   // 0.125 * log2(e): softmax done in base-2

// ---------------- fp32 -> bf16 convert (8 elems/thread) ----------------
__global__ void cvt_bf16_k(const float* __restrict__ s, u16* __restrict__ d, int n8) {
  int i = blockIdx.x * blockDim.x + threadIdx.x;
  int stride = gridDim.x * blockDim.x;
  for (; i < n8; i += stride) {
    float4 a = ((const float4*)s)[2 * i];
    float4 b = ((const float4*)s)[2 * i + 1];
    uint4 o;
    o.x = (u32)f2b(a.x) | ((u32)f2b(a.y) << 16);
    o.y = (u32)f2b(a.z) | ((u32)f2b(a.w) << 16);
    o.z = (u32)f2b(b.x) | ((u32)f2b(b.y) << 16);
    o.w = (u32)f2b(b.z) | ((u32)f2b(b.w) << 16);
    ((uint4*)d)[i] = o;
  }
}

// ---------------- bf16 GEMM, C = A * B^T (+bias), m97 structure ----------------
// MODE 0 (BM=128): N=3072, scatter bf16 into q/k/v [2,16,2048,64]; q pre-scaled by SCALE_Q.
// MODE 1 (BM=64):  N=1024, write fp32 to outf.
template <int MODE, int BM>
__global__ __launch_bounds__(256) void gemm_bt(
    const u16* __restrict__ A, const u16* __restrict__ Bm,
    const float* __restrict__ bias,
    u16* __restrict__ q, u16* __restrict__ k, u16* __restrict__ v,
    float* __restrict__ outf) {
  constexpr int KD = 1024;
  constexpr int MR = BM / 32;              // row-frags per wave
  const int n0 = blockIdx.x * 128;
  const int m0 = blockIdx.y * BM;
  const int tid = threadIdx.x;
  const int wid = tid >> 6;
  const int lane = tid & 63;
  const int wr = wid >> 1, wc = wid & 1;   // 2x2 waves; wave tile (BM/2) x 64
  const int fr = lane & 15, fg = lane >> 4;
  const int srow = lane >> 2;
  const int scol = (lane & 3) * 8;

  __shared__ __align__(16) u16 As[BM * 32];
  __shared__ __align__(16) u16 Bs[128 * 32];

  f32x4 acc[MR][4] = {};

  for (int k0 = 0; k0 < KD; k0 += 32) {
#pragma unroll
    for (int i = 0; i < BM / 64; ++i) {
      int row = i * 64 + wid * 16 + srow;
      gload16(A + (size_t)(m0 + row) * KD + k0 + scol, As + (i * 64 + wid * 16) * 32);
    }
#pragma unroll
    for (int i = 0; i < 2; ++i) {
      int row = i * 64 + wid * 16 + srow;
      gload16(Bm + (size_t)(n0 + row) * KD + k0 + scol, Bs + (i * 64 + wid * 16) * 32);
    }
    __syncthreads();
    bf16x8 af[MR], bfr[4];
#pragma unroll
    for (int r = 0; r < MR; ++r)
      af[r] = *(const bf16x8*)(As + (wr * (BM / 2) + r * 16 + fr) * 32 + fg * 8);
#pragma unroll
    for (int c = 0; c < 4; ++c)
      bfr[c] = *(const bf16x8*)(Bs + (wc * 64 + c * 16 + fr) * 32 + fg * 8);
#pragma unroll
    for (int r = 0; r < MR; ++r)
#pragma unroll
      for (int c = 0; c < 4; ++c)
        acc[r][c] = __builtin_amdgcn_mfma_f32_16x16x32_bf16(af[r], bfr[c], acc[r][c], 0, 0, 0);
    __syncthreads();
  }

#pragma unroll
  for (int r = 0; r < MR; ++r) {
#pragma unroll
    for (int c = 0; c < 4; ++c) {
      const int gcol = n0 + wc * 64 + c * 16 + fr;
      const float bv = bias[gcol];
#pragma unroll
      for (int g = 0; g < 4; ++g) {
        const int grow = m0 + wr * (BM / 2) + r * 16 + fg * 4 + g;
        float val = acc[r][c][g] + bv;
        if (MODE == 0) {
          const int which = gcol >> 10;          // 0=q 1=k 2=v
          if (which == 0) val *= SCALE_Q;        // bake softmax scale into Q
          const int dcol = gcol & 1023;
          const int hh = dcol >> 6, dd = dcol & 63;
          const int bb = grow >> 11, ss = grow & 2047;
          u16* dst = which == 0 ? q : (which == 1 ? k : v);
          dst[((size_t)((bb << 4) + hh) * 2048 + ss) * 64 + dd] = f2b(val);
        } else {
          outf[(size_t)grow * 1024 + gcol] = val;
        }
      }
    }
  }
}

// ---------------- flash attention fwd: swapped-QK, in-register softmax ----------------
// Q,K,V: [32 bh][2048][64] bf16 (Q pre-scaled by SCALE_Q). AO: [4096][1024] bf16.
//
// Per wave: 32 q rows (2 rf subtiles of 16). S^T = mfma(K_frag, Q_frag):
//   lane holds q = lane&15, scores for physical key rows {16c + 4*fg + g}.
// K is staged key-permuted: LDS physical row r <- logical key L(r),
//   L(r) = bits [c1 f1 f0 c0 g1 g0] of r=[c1 c0 f1 f0 g1 g0], so the lane-held
//   set IS the PV A-frag set {32ks + 8*fg + j} in order: pack-only, no shuffles.
__global__ __launch_bounds__(256) void attn_fwd(
    const u16* __restrict__ Q, const u16* __restrict__ K,
    const u16* __restrict__ V, u16* __restrict__ AO) {
  const int wg = blockIdx.x;                // 512
  const int newid = (wg & 7) * 64 + (wg >> 3);   // XCD swizzle: 4 bh per XCD (KV L2-hot)
  const int bh = newid >> 4;
  const int qt = newid & 15;
  const int b = bh >> 4, h = bh & 15;

  const int tid = threadIdx.x, wid = tid >> 6, lane = tid & 63;
  const int fr = lane & 15, fg = lane >> 4;
  const size_t base = (size_t)bh * (2048 * 64);
  const int q0 = qt * 128 + wid * 32;

  constexpr int LD = 72;                    // pad: b128 reads bank-uniform
  __shared__ __align__(16) u16 Ks[2][64 * LD];
  __shared__ __align__(16) u16 Vs[2][64 * LD];   // transposed: Vs[d][key_logical]

  // Q fragments (already scaled)
  bf16x8 qf[2][2];
#pragma unroll
  for (int rf = 0; rf < 2; ++rf)
#pragma unroll
    for (int ks = 0; ks < 2; ++ks)
      qf[rf][ks] = *(const bf16x8*)(Q + base + (size_t)(q0 + rf * 16 + fr) * 64 + ks * 32 + fg * 8);

  f32x4 o[2][4] = {};
  float mrow[2] = {-3.0e38f, -3.0e38f};     // per lane: q = q0 + rf*16 + fr
  float lrow[2] = {0.f, 0.f};

  const int krow = lane;                    // physical LDS row this lane stages
  // logical source row for permuted K staging
  const int Lrow = ((krow >> 5) << 5) | (((krow >> 3) & 1) << 4) | (((krow >> 2) & 1) << 3) |
                   (((krow >> 4) & 1) << 2) | (krow & 3);
  const int c0 = wid * 16;                  // this wave's d-column slice for staging

  uint4 kr0, kr1, vr0, vr1;
  {
    const u16* kp = K + base + (size_t)Lrow * 64 + c0;
    const u16* vp = V + base + (size_t)krow * 64 + c0;
    kr0 = *(const uint4*)kp; kr1 = *(const uint4*)(kp + 8);
    vr0 = *(const uint4*)vp; vr1 = *(const uint4*)(vp + 8);
  }

  for (int t = 0; t < 32; ++t) {
    u16* kb = (u16*)Ks[t & 1];
    u16* vb = (u16*)Vs[t & 1];
    // stage tile t (regs -> LDS)
    *(uint4*)(kb + krow * LD + c0) = kr0;
    *(uint4*)(kb + krow * LD + c0 + 8) = kr1;
    {
      u32 vv[8] = {vr0.x, vr0.y, vr0.z, vr0.w, vr1.x, vr1.y, vr1.z, vr1.w};
#pragma unroll
      for (int j = 0; j < 8; ++j) {
        vb[(c0 + 2 * j) * LD + krow]     = (u16)(vv[j] & 0xffffu);
        vb[(c0 + 2 * j + 1) * LD + krow] = (u16)(vv[j] >> 16);
      }
    }
    __syncthreads();
    if (t + 1 < 32) {                       // T14: next-tile loads fly under compute
      const u16* kp = K + base + (size_t)((t + 1) * 64 + Lrow) * 64 + c0;
      const u16* vp = V + base + (size_t)((t + 1) * 64 + krow) * 64 + c0;
      kr0 = *(const uint4*)kp; kr1 = *(const uint4*)(kp + 8);
      vr0 = *(const uint4*)vp; vr1 = *(const uint4*)(vp + 8);
    }

    // K/V fragments shared by both rf
    bf16x8 kf[4][2], vf[4][2];
#pragma unroll
    for (int c = 0; c < 4; ++c)
#pragma unroll
      for (int ks = 0; ks < 2; ++ks)
        kf[c][ks] = *(const bf16x8*)(kb + (c * 16 + fr) * LD + ks * 32 + fg * 8);
#pragma unroll
    for (int d = 0; d < 4; ++d)
#pragma unroll
      for (int ks = 0; ks < 2; ++ks)
        vf[d][ks] = *(const bf16x8*)(vb + (d * 16 + fr) * LD + ks * 32 + fg * 8);

#pragma unroll
    for (int rf = 0; rf < 2; ++rf) {
      // S^T = K · Q^T  (lane: q = fr, physical keys {16c+4fg+g})
      f32x4 p[4];
#pragma unroll
      for (int c = 0; c < 4; ++c) {
        f32x4 z = {};
        z = __builtin_amdgcn_mfma_f32_16x16x32_bf16(kf[c][0], qf[rf][0], z, 0, 0, 0);
        z = __builtin_amdgcn_mfma_f32_16x16x32_bf16(kf[c][1], qf[rf][1], z, 0, 0, 0);
        p[c] = z;
      }
      // row max (16 local + across fg)
      f32x4 m4 = p[0];
#pragma unroll
      for (int c = 1; c < 4; ++c) {
        m4[0] = fmaxf(m4[0], p[c][0]); m4[1] = fmaxf(m4[1], p[c][1]);
        m4[2] = fmaxf(m4[2], p[c][2]); m4[3] = fmaxf(m4[3], p[c][3]);
      }
      float mx = fmaxf(fmaxf(m4[0], m4[1]), fmaxf(m4[2], m4[3]));
      mx = fmaxf(mx, __shfl_xor(mx, 16));
      mx = fmaxf(mx, __shfl_xor(mx, 32));
      const float mold = mrow[rf];
      const float mnew = fmaxf(mold, mx);
      const float corr = exp2f(mold - mnew);
      mrow[rf] = mnew;
      float rs = 0.f;
#pragma unroll
      for (int c = 0; c < 4; ++c)
#pragma unroll
        for (int g = 0; g < 4; ++g) {
          const float pv = exp2f(p[c][g] - mnew);
          p[c][g] = pv;
          rs += pv;
        }
      rs += __shfl_xor(rs, 16);
      rs += __shfl_xor(rs, 32);
      lrow[rf] = lrow[rf] * corr + rs;

      // P -> bf16 A-frags; key-permutation makes this pack-only
      bf16x8 pa[2];
#pragma unroll
      for (int ks = 0; ks < 2; ++ks) {
        u32 w0 = pk2(p[2 * ks][0], p[2 * ks][1]);
        u32 w1 = pk2(p[2 * ks][2], p[2 * ks][3]);
        u32 w2 = pk2(p[2 * ks + 1][0], p[2 * ks + 1][1]);
        u32 w3 = pk2(p[2 * ks + 1][2], p[2 * ks + 1][3]);
        uint4 packed = {w0, w1, w2, w3};
        pa[ks] = __builtin_bit_cast(bf16x8, packed);
      }

      // rescale O (O-basis rows q = 4*fg+g: fetch corr from lane 20*fg+g)
      float cO[4];
#pragma unroll
      for (int g = 0; g < 4; ++g) cO[g] = __shfl(corr, 20 * fg + g);
#pragma unroll
      for (int d = 0; d < 4; ++d) {
        o[rf][d][0] *= cO[0]; o[rf][d][1] *= cO[1];
        o[rf][d][2] *= cO[2]; o[rf][d][3] *= cO[3];
      }
      // PV accumulate
#pragma unroll
      for (int d = 0; d < 4; ++d) {
        o[rf][d] = __builtin_amdgcn_mfma_f32_16x16x32_bf16(pa[0], vf[d][0], o[rf][d], 0, 0, 0);
        o[rf][d] = __builtin_amdgcn_mfma_f32_16x16x32_bf16(pa[1], vf[d][1], o[rf][d], 0, 0, 0);
      }
    }
  }

  // epilogue
#pragma unroll
  for (int rf = 0; rf < 2; ++rf) {
    float lO[4], rinv[4];
#pragma unroll
    for (int g = 0; g < 4; ++g) lO[g] = __shfl(lrow[rf], 20 * fg + g);
#pragma unroll
    for (int g = 0; g < 4; ++g) rinv[g] = 1.0f / lO[g];
#pragma unroll
    for (int d = 0; d < 4; ++d)
#pragma unroll
      for (int g = 0; g < 4; ++g) {
        const int qr = q0 + rf * 16 + fg * 4 + g;
        AO[(size_t)(b * 2048 + qr) * 1024 + h * 64 + d * 16 + fr] = f2b(o[rf][d][g] * rinv[g]);
      }
  }
}

// ---------------- launch ----------------
extern "C" void kernel_launch(void* const* d_in, const int* in_sizes, int n_in,
                              void* d_out, int out_size, void* d_ws, size_t ws_size,
                              hipStream_t stream) {
  (void)in_sizes; (void)n_in; (void)out_size; (void)ws_size;
  const float* x     = (const float*)d_in[0];
  const float* w_in  = (const float*)d_in[1];
  const float* b_in  = (const float*)d_in[2];
  const float* w_out = (const float*)d_in[3];
  const float* b_out = (const float*)d_in[4];

  u16* xb    = (u16*)d_ws;                       // [4096,1024]
  u16* winb  = xb    + (size_t)4096 * 1024;      // [3072,1024]
  u16* woutb = winb  + (size_t)3072 * 1024;      // [1024,1024]
  u16* qb    = woutb + (size_t)1024 * 1024;      // [32,2048,64]
  u16* kb    = qb    + (size_t)4194304;
  u16* vb    = kb    + (size_t)4194304;
  u16* aob   = vb    + (size_t)4194304;          // [4096,1024]

  cvt_bf16_k<<<2048, 256, 0, stream>>>(x, xb, 4096 * 1024 / 8);
  cvt_bf16_k<<<1536, 256, 0, stream>>>(w_in, winb, 3072 * 1024 / 8);
  cvt_bf16_k<<<512, 256, 0, stream>>>(w_out, woutb, 1024 * 1024 / 8);

  gemm_bt<0, 128><<<dim3(24, 32), 256, 0, stream>>>(xb, winb, b_in, qb, kb, vb, nullptr);
  attn_fwd<<<512, 256, 0, stream>>>(qb, kb, vb, aob);
  gemm_bt<1, 64><<<dim3(8, 64), 256, 0, stream>>>(aob, woutb, b_out, nullptr, nullptr, nullptr,
                                                  (float*)d_out);
}

// Round 5
// 199.043 us; speedup vs baseline: 1.2934x; 1.1151x over previous
//
#include <hip/hip_runtime.h>

using u16 = unsigned short;
using u32 = unsigned int;

typedef __bf16 bf16x8 __attribute__((ext_vector_type(8)));
typedef __bf16 bf16x2 __attribute__((ext_vector_type(2)));
typedef float f32x4 __attribute__((ext_vector_type(4)));

__device__ __forceinline__ u16 f2b(float x) {
  u32 u = __builtin_bit_cast(u32, x);
  u += 0x7fffu + ((u >> 16) & 1u);   // RNE
  return (u16)(u >> 16);
}

// pack two f32 -> bf16x2 (low = first)
__device__ __forceinline__ u32 pk2(float lo, float hi) {
  bf16x2 t;
  t[0] = (__bf16)lo;
  t[1] = (__bf16)hi;
  return __builtin_bit_cast(u32, t);
}

__device__ __forceinline__ void gload16(const u16* g, u16* l) {
  __builtin_amdgcn_global_load_lds(
      (const __attribute__((address_space(1))) void*)g,
      (__attribute__((address_space(3))) void*)l, 16, 0, 0);
}

#define SCALE_Q 0.1803368801111204f   // 0.125 * log2(e): softmax in base-2
#define DEFER_THR 8.0f                // T13: P bounded by 2^8, fine in bf16/f32

// ---------------- fp32 -> bf16 convert (8 elems/thread) ----------------
__global__ void cvt_bf16_k(const float* __restrict__ s, u16* __restrict__ d, int n8) {
  int i = blockIdx.x * blockDim.x + threadIdx.x;
  int stride = gridDim.x * blockDim.x;
  for (; i < n8; i += stride) {
    float4 a = ((const float4*)s)[2 * i];
    float4 b = ((const float4*)s)[2 * i + 1];
    uint4 o;
    o.x = (u32)f2b(a.x) | ((u32)f2b(a.y) << 16);
    o.y = (u32)f2b(a.z) | ((u32)f2b(a.w) << 16);
    o.z = (u32)f2b(b.x) | ((u32)f2b(b.y) << 16);
    o.w = (u32)f2b(b.z) | ((u32)f2b(b.w) << 16);
    ((uint4*)d)[i] = o;
  }
}

// ---------------- bf16 GEMM, C = A * B^T (+bias), m97 structure ----------------
template <int MODE, int BM>
__global__ __launch_bounds__(256) void gemm_bt(
    const u16* __restrict__ A, const u16* __restrict__ Bm,
    const float* __restrict__ bias,
    u16* __restrict__ q, u16* __restrict__ k, u16* __restrict__ v,
    float* __restrict__ outf) {
  constexpr int KD = 1024;
  constexpr int MR = BM / 32;
  const int n0 = blockIdx.x * 128;
  const int m0 = blockIdx.y * BM;
  const int tid = threadIdx.x;
  const int wid = tid >> 6;
  const int lane = tid & 63;
  const int wr = wid >> 1, wc = wid & 1;
  const int fr = lane & 15, fg = lane >> 4;
  const int srow = lane >> 2;
  const int scol = (lane & 3) * 8;

  __shared__ __align__(16) u16 As[BM * 32];
  __shared__ __align__(16) u16 Bs[128 * 32];

  f32x4 acc[MR][4] = {};

  for (int k0 = 0; k0 < KD; k0 += 32) {
#pragma unroll
    for (int i = 0; i < BM / 64; ++i) {
      int row = i * 64 + wid * 16 + srow;
      gload16(A + (size_t)(m0 + row) * KD + k0 + scol, As + (i * 64 + wid * 16) * 32);
    }
#pragma unroll
    for (int i = 0; i < 2; ++i) {
      int row = i * 64 + wid * 16 + srow;
      gload16(Bm + (size_t)(n0 + row) * KD + k0 + scol, Bs + (i * 64 + wid * 16) * 32);
    }
    __syncthreads();
    bf16x8 af[MR], bfr[4];
#pragma unroll
    for (int r = 0; r < MR; ++r)
      af[r] = *(const bf16x8*)(As + (wr * (BM / 2) + r * 16 + fr) * 32 + fg * 8);
#pragma unroll
    for (int c = 0; c < 4; ++c)
      bfr[c] = *(const bf16x8*)(Bs + (wc * 64 + c * 16 + fr) * 32 + fg * 8);
#pragma unroll
    for (int r = 0; r < MR; ++r)
#pragma unroll
      for (int c = 0; c < 4; ++c)
        acc[r][c] = __builtin_amdgcn_mfma_f32_16x16x32_bf16(af[r], bfr[c], acc[r][c], 0, 0, 0);
    __syncthreads();
  }

#pragma unroll
  for (int r = 0; r < MR; ++r) {
#pragma unroll
    for (int c = 0; c < 4; ++c) {
      const int gcol = n0 + wc * 64 + c * 16 + fr;
      const float bv = bias[gcol];
#pragma unroll
      for (int g = 0; g < 4; ++g) {
        const int grow = m0 + wr * (BM / 2) + r * 16 + fg * 4 + g;
        float val = acc[r][c][g] + bv;
        if (MODE == 0) {
          const int which = gcol >> 10;          // 0=q 1=k 2=v
          if (which == 0) val *= SCALE_Q;
          const int dcol = gcol & 1023;
          const int hh = dcol >> 6, dd = dcol & 63;
          const int bb = grow >> 11, ss = grow & 2047;
          u16* dst = which == 0 ? q : (which == 1 ? k : v);
          dst[((size_t)((bb << 4) + hh) * 2048 + ss) * 64 + dd] = f2b(val);
        } else {
          outf[(size_t)grow * 1024 + gcol] = val;
        }
      }
    }
  }
}

// ---------------- flash attention fwd: swapped-QK, in-register softmax ----------------
// Q,K,V: [32 bh][2048][64] bf16 (Q pre-scaled). AO: [4096][1024] bf16.
__global__ __launch_bounds__(256) void attn_fwd(
    const u16* __restrict__ Q, const u16* __restrict__ K,
    const u16* __restrict__ V, u16* __restrict__ AO) {
  const int wg = blockIdx.x;                     // 512
  const int newid = (wg & 7) * 64 + (wg >> 3);   // XCD swizzle (bijective: 512%8==0)
  const int bh = newid >> 4;
  const int qt = newid & 15;
  const int b = bh >> 4, h = bh & 15;

  const int tid = threadIdx.x, wid = tid >> 6, lane = tid & 63;
  const int fr = lane & 15, fg = lane >> 4;
  const size_t base = (size_t)bh * (2048 * 64);
  const int q0 = qt * 128 + wid * 32;

  constexpr int LD = 72;
  __shared__ __align__(16) u16 Ks[2][64 * LD];
  __shared__ __align__(16) u16 Vs[2][64 * LD];   // transposed: Vs[d][key_logical]

  bf16x8 qf[2][2];
#pragma unroll
  for (int rf = 0; rf < 2; ++rf)
#pragma unroll
    for (int ks = 0; ks < 2; ++ks)
      qf[rf][ks] = *(const bf16x8*)(Q + base + (size_t)(q0 + rf * 16 + fr) * 64 + ks * 32 + fg * 8);

  f32x4 o[2][4] = {};
  float mrow[2] = {-3.0e38f, -3.0e38f};
  float lrow[2] = {0.f, 0.f};

  const int krow = lane;
  // K staged key-permuted: phys row r <- logical L(r) so PV A-frag is pack-only
  const int Lrow = ((krow >> 5) << 5) | (((krow >> 3) & 1) << 4) | (((krow >> 2) & 1) << 3) |
                   (((krow >> 4) & 1) << 2) | (krow & 3);
  const int c0 = wid * 16;                  // wave's d-column slice
  const int kp2 = (lane & 31) * 2;          // V staging: key pair
  const int vh = (lane >> 5) * 8;           // V staging: d sub-slice

  uint4 kr0, kr1, vr0, vr1;
  {
    const u16* kp = K + base + (size_t)Lrow * 64 + c0;
    const u16* vp = V + base + (size_t)kp2 * 64 + c0 + vh;
    kr0 = *(const uint4*)kp; kr1 = *(const uint4*)(kp + 8);
    vr0 = *(const uint4*)vp; vr1 = *(const uint4*)(vp + 64);
  }

  for (int t = 0; t < 32; ++t) {
    u16* kb = (u16*)Ks[t & 1];
    u16* vb = (u16*)Vs[t & 1];
    // stage tile t
    *(uint4*)(kb + krow * LD + c0) = kr0;
    *(uint4*)(kb + krow * LD + c0 + 8) = kr1;
    {
      const u32* ra = (const u32*)&vr0;
      const u32* rb = (const u32*)&vr1;
#pragma unroll
      for (int j = 0; j < 8; ++j) {   // w = V[kp2][d] | V[kp2+1][d]<<16, one v_perm each
        u32 w = __builtin_amdgcn_perm(rb[j >> 1], ra[j >> 1],
                                      (j & 1) ? 0x07060302u : 0x05040100u);
        *(u32*)(vb + (c0 + vh + j) * LD + kp2) = w;
      }
    }
    __syncthreads();
    if (t + 1 < 32) {                       // T14: next-tile loads fly under compute
      const u16* kp = K + base + (size_t)((t + 1) * 64 + Lrow) * 64 + c0;
      const u16* vp = V + base + (size_t)((t + 1) * 64 + kp2) * 64 + c0 + vh;
      kr0 = *(const uint4*)kp; kr1 = *(const uint4*)(kp + 8);
      vr0 = *(const uint4*)vp; vr1 = *(const uint4*)(vp + 64);
    }

    bf16x8 kf[4][2], vf[4][2];
#pragma unroll
    for (int c = 0; c < 4; ++c)
#pragma unroll
      for (int ks = 0; ks < 2; ++ks)
        kf[c][ks] = *(const bf16x8*)(kb + (c * 16 + fr) * LD + ks * 32 + fg * 8);
#pragma unroll
    for (int d = 0; d < 4; ++d)
#pragma unroll
      for (int ks = 0; ks < 2; ++ks)
        vf[d][ks] = *(const bf16x8*)(vb + (d * 16 + fr) * LD + ks * 32 + fg * 8);

#pragma unroll
    for (int rf = 0; rf < 2; ++rf) {
      f32x4 p[4];
      __builtin_amdgcn_s_setprio(1);
#pragma unroll
      for (int c = 0; c < 4; ++c) {
        f32x4 z = {};
        z = __builtin_amdgcn_mfma_f32_16x16x32_bf16(kf[c][0], qf[rf][0], z, 0, 0, 0);
        z = __builtin_amdgcn_mfma_f32_16x16x32_bf16(kf[c][1], qf[rf][1], z, 0, 0, 0);
        p[c] = z;
      }
      __builtin_amdgcn_s_setprio(0);
      // row max over 16 local + fg groups
      f32x4 m4 = p[0];
#pragma unroll
      for (int c = 1; c < 4; ++c) {
        m4[0] = fmaxf(m4[0], p[c][0]); m4[1] = fmaxf(m4[1], p[c][1]);
        m4[2] = fmaxf(m4[2], p[c][2]); m4[3] = fmaxf(m4[3], p[c][3]);
      }
      float mx = fmaxf(fmaxf(m4[0], m4[1]), fmaxf(m4[2], m4[3]));
      mx = fmaxf(mx, __shfl_xor(mx, 16));
      mx = fmaxf(mx, __shfl_xor(mx, 32));

      const float mold = mrow[rf];
      const bool defer = __all(mx <= mold + DEFER_THR);   // T13: wave-uniform skip
      float mnew = mold, corr = 1.0f;
      if (!defer) {
        mnew = fmaxf(mold, mx);
        corr = __builtin_amdgcn_exp2f(mold - mnew);
        mrow[rf] = mnew;
      }
      float rs = 0.f;
#pragma unroll
      for (int c = 0; c < 4; ++c)
#pragma unroll
        for (int g = 0; g < 4; ++g) {
          const float pv = __builtin_amdgcn_exp2f(p[c][g] - mnew);
          p[c][g] = pv;
          rs += pv;
        }
      rs += __shfl_xor(rs, 16);
      rs += __shfl_xor(rs, 32);
      if (defer) {
        lrow[rf] += rs;
      } else {
        lrow[rf] = lrow[rf] * corr + rs;
        float cO[4];
#pragma unroll
        for (int g = 0; g < 4; ++g) cO[g] = __shfl(corr, 20 * fg + g);
#pragma unroll
        for (int d = 0; d < 4; ++d) {
          o[rf][d][0] *= cO[0]; o[rf][d][1] *= cO[1];
          o[rf][d][2] *= cO[2]; o[rf][d][3] *= cO[3];
        }
      }

      bf16x8 pa[2];
#pragma unroll
      for (int ks = 0; ks < 2; ++ks) {
        u32 w0 = pk2(p[2 * ks][0], p[2 * ks][1]);
        u32 w1 = pk2(p[2 * ks][2], p[2 * ks][3]);
        u32 w2 = pk2(p[2 * ks + 1][0], p[2 * ks + 1][1]);
        u32 w3 = pk2(p[2 * ks + 1][2], p[2 * ks + 1][3]);
        uint4 packed = {w0, w1, w2, w3};
        pa[ks] = __builtin_bit_cast(bf16x8, packed);
      }
      __builtin_amdgcn_s_setprio(1);
#pragma unroll
      for (int d = 0; d < 4; ++d) {
        o[rf][d] = __builtin_amdgcn_mfma_f32_16x16x32_bf16(pa[0], vf[d][0], o[rf][d], 0, 0, 0);
        o[rf][d] = __builtin_amdgcn_mfma_f32_16x16x32_bf16(pa[1], vf[d][1], o[rf][d], 0, 0, 0);
      }
      __builtin_amdgcn_s_setprio(0);
    }
  }

  // epilogue
#pragma unroll
  for (int rf = 0; rf < 2; ++rf) {
    float rinv[4];
#pragma unroll
    for (int g = 0; g < 4; ++g)
      rinv[g] = __builtin_amdgcn_rcpf(__shfl(lrow[rf], 20 * fg + g));
#pragma unroll
    for (int d = 0; d < 4; ++d)
#pragma unroll
      for (int g = 0; g < 4; ++g) {
        const int qr = q0 + rf * 16 + fg * 4 + g;
        AO[(size_t)(b * 2048 + qr) * 1024 + h * 64 + d * 16 + fr] = f2b(o[rf][d][g] * rinv[g]);
      }
  }
}

// ---------------- launch ----------------
extern "C" void kernel_launch(void* const* d_in, const int* in_sizes, int n_in,
                              void* d_out, int out_size, void* d_ws, size_t ws_size,
                              hipStream_t stream) {
  (void)in_sizes; (void)n_in; (void)out_size; (void)ws_size;
  const float* x     = (const float*)d_in[0];
  const float* w_in  = (const float*)d_in[1];
  const float* b_in  = (const float*)d_in[2];
  const float* w_out = (const float*)d_in[3];
  const float* b_out = (const float*)d_in[4];

  u16* xb    = (u16*)d_ws;                       // [4096,1024]
  u16* winb  = xb    + (size_t)4096 * 1024;      // [3072,1024]
  u16* woutb = winb  + (size_t)3072 * 1024;      // [1024,1024]
  u16* qb    = woutb + (size_t)1024 * 1024;      // [32,2048,64]
  u16* kb    = qb    + (size_t)4194304;
  u16* vb    = kb    + (size_t)4194304;
  u16* aob   = vb    + (size_t)4194304;          // [4096,1024]

  cvt_bf16_k<<<2048, 256, 0, stream>>>(x, xb, 4096 * 1024 / 8);
  cvt_bf16_k<<<1536, 256, 0, stream>>>(w_in, winb, 3072 * 1024 / 8);
  cvt_bf16_k<<<512, 256, 0, stream>>>(w_out, woutb, 1024 * 1024 / 8);

  gemm_bt<0, 128><<<dim3(24, 32), 256, 0, stream>>>(xb, winb, b_in, qb, kb, vb, nullptr);
  attn_fwd<<<512, 256, 0, stream>>>(qb, kb, vb, aob);
  gemm_bt<1, 64><<<dim3(8, 64), 256, 0, stream>>>(aob, woutb, b_out, nullptr, nullptr, nullptr,
                                                  (float*)d_out);
}